// Round 1
// baseline (252.643 us; speedup 1.0000x reference)
//
#include <hip/hip_runtime.h>

// BezierSurfaceFitter: out[b,c,i,j] = sum_{p,q} K[b,c,p,q] * bu[i,p] * bv[j,q]
// B=256, C=3, H=W=256, M=N=31.  bu == bv (same Bernstein table, 256x32).
//
// Strategy:
//   kernel 1: compute Bernstein basis table Bt[i][k] (256x32 fp32, fp64 math)
//             into d_ws (32 KB).
//   kernel 2: one block per (b,c) [768 blocks], 256 threads, thread owns
//             column j = tid.  Stage 2 (T[p] = sum_q K[bc,p,q]*B[j,q]) and
//             stage 3 (out[i,j] = sum_p B[i,p]*T[p]) both keep T in 32 VGPRs
//             -> no LDS, no barriers.  K and bu rows are wave-uniform ->
//             scalar loads.  Stores are fully coalesced (lane = j).

#define DEG 31

__global__ __launch_bounds__(256) void bez_basis_kernel(float* __restrict__ B) {
    int g = blockIdx.x * 256 + threadIdx.x;   // 0..8191
    int i = g >> 5;                            // sample index 0..255
    int k = g & 31;                            // basis index 0..31
    double t = ((double)i + 0.5) / 256.0;
    // C(31,k) exactly in double (all intermediates < 2^53, each prefix integer)
    double coeff = 1.0;
    for (int kk = 1; kk <= k; ++kk)
        coeff = coeff * (double)(DEG - kk + 1) / (double)kk;
    double tk = 1.0;
    for (int e = 0; e < k; ++e) tk *= t;
    double omt = 1.0 - t;
    double tq = 1.0;
    for (int e = 0; e < DEG - k; ++e) tq *= omt;
    B[g] = (float)(coeff * tk * tq);
}

__global__ __launch_bounds__(256) void bez_main_kernel(
        const float* __restrict__ K,   // (768, 32, 32)
        const float* __restrict__ B,   // (256, 32) basis table
        float* __restrict__ out) {     // (768, 256, 256)
    const int bc  = blockIdx.x;        // 0..767
    const int tid = threadIdx.x;       // j = tid, 0..255

    // ---- load this thread's basis row B[j][*] into registers (float4 x8) ----
    float breg[32];
    const float4* brow = (const float4*)(B + tid * 32);
    #pragma unroll
    for (int q4 = 0; q4 < 8; ++q4) {
        float4 v = brow[q4];
        breg[q4 * 4 + 0] = v.x;
        breg[q4 * 4 + 1] = v.y;
        breg[q4 * 4 + 2] = v.z;
        breg[q4 * 4 + 3] = v.w;
    }

    // ---- stage 2: T[p] = sum_q K[bc,p,q] * B[j,q]  (K uniform -> s_load) ----
    const float* Kbc = K + (size_t)bc * 1024;
    float treg[32];
    #pragma unroll
    for (int p = 0; p < 32; ++p) {
        float acc = 0.0f;
        #pragma unroll
        for (int q = 0; q < 32; ++q)
            acc += Kbc[p * 32 + q] * breg[q];
        treg[p] = acc;
    }

    // ---- stage 3: out[i,j] = sum_p B[i,p] * T[p]  (bu row uniform -> s_load) ----
    float* outbc = out + (size_t)bc * 65536;
    #pragma unroll 4
    for (int i = 0; i < 256; ++i) {
        const float* bu = B + i * 32;
        float acc = 0.0f;
        #pragma unroll
        for (int p = 0; p < 32; ++p)
            acc += bu[p] * treg[p];
        outbc[i * 256 + tid] = acc;
    }
}

extern "C" void kernel_launch(void* const* d_in, const int* in_sizes, int n_in,
                              void* d_out, int out_size, void* d_ws, size_t ws_size,
                              hipStream_t stream) {
    // d_in[0] = x (int32, ignored), d_in[1] = K_mat (256*3*32*32 fp32)
    const float* K = (const float*)d_in[1];
    float* B   = (float*)d_ws;     // 256*32 fp32 = 32 KB scratch
    float* out = (float*)d_out;    // 768*256*256 fp32

    bez_basis_kernel<<<dim3(32), dim3(256), 0, stream>>>(B);
    bez_main_kernel<<<dim3(768), dim3(256), 0, stream>>>(K, B, out);
}

// Round 2
// 219.139 us; speedup vs baseline: 1.1529x; 1.1529x over previous
//
#include <hip/hip_runtime.h>

// BezierSurfaceFitter via MFMA.
// out[bc,i,j] = sum_p Bu[i,p] * T[bc,p,j],  T[bc,p,j] = sum_q K[bc,p,q]*Bv[j,q]
// Bu == Bv (256x32 Bernstein table). Per bc: (256x32)@(32x256) GEMM, K=32 ->
// exactly one K-step of mfma_f32_16x16x32_bf16. Both operands split into
// bf16 hi+lo; out = Ah*Bh + Ah*Bl + Al*Bh (drop lo*lo) ~ fp32 accuracy.
//
// Kernel 1 (tiny): Bernstein table fp32 + bf16 hi/lo tables into d_ws.
// Kernel 2: 768 blocks (one per bc) x 256 threads.
//   phase 1: thread j computes T[p][j] (fp32 VALU, K rows wave-uniform ->
//            s_load), splits to bf16 hi/lo, writes B-operand fragments to
//            XOR-swizzled LDS (bank-balanced ds_read_b128 in phase 2).
//   phase 2: wave w owns tile-rows ti=4w..4w+3; A-frags (Bu hi/lo) loaded
//            once from global (L1/L2-hot, same 64KB for all blocks); loop
//            tj=0..15: 2 ds_read_b128 + 12 MFMA + 16 coalesced-ish stores.

#define DEG 31

typedef short bf16x8 __attribute__((ext_vector_type(8)));  // 8 bf16 in 4 VGPRs
typedef float f32x4  __attribute__((ext_vector_type(4)));

__device__ __forceinline__ unsigned short f2bf_rne(float x) {
    unsigned int u = __float_as_uint(x);
    unsigned int r = (u + 0x7FFFu + ((u >> 16) & 1u)) >> 16;
    return (unsigned short)r;
}
__device__ __forceinline__ float bf2f(unsigned short h) {
    return __uint_as_float(((unsigned int)h) << 16);
}

// ---- kernel 1: basis tables -------------------------------------------------
__global__ __launch_bounds__(256) void bez_basis_kernel(
        float* __restrict__ Bt,            // (256,32) fp32
        unsigned short* __restrict__ Hi,   // (256,32) bf16 bits (hi)
        unsigned short* __restrict__ Lo) { // (256,32) bf16 bits (lo)
    int g = blockIdx.x * 256 + threadIdx.x;   // 0..8191
    int i = g >> 5;
    int k = g & 31;
    double t = ((double)i + 0.5) / 256.0;
    double coeff = 1.0;
    for (int kk = 1; kk <= k; ++kk)
        coeff = coeff * (double)(DEG - kk + 1) / (double)kk;
    double tk = 1.0;
    for (int e = 0; e < k; ++e) tk *= t;
    double omt = 1.0 - t;
    double tq = 1.0;
    for (int e = 0; e < DEG - k; ++e) tq *= omt;
    float v = (float)(coeff * tk * tq);
    Bt[g] = v;
    unsigned short h = f2bf_rne(v);
    Hi[g] = h;
    Lo[g] = f2bf_rne(v - bf2f(h));
}

// ---- kernel 2: main ---------------------------------------------------------
__global__ __launch_bounds__(256) void bez_main_kernel(
        const float* __restrict__ K,             // (768,32,32) fp32
        const float* __restrict__ Bt,            // (256,32) fp32
        const unsigned short* __restrict__ Hi,   // (256,32) bf16 hi
        const unsigned short* __restrict__ Lo,   // (256,32) bf16 lo
        float* __restrict__ out) {               // (768,256,256) fp32
    // LDS: T as B-operand fragments, hi/lo. Layout: [n][c]*8 bf16, 16B blocks,
    // XOR-swizzled block index (c ^ (n&3)) -> bank-balanced b128 access.
    __shared__ __align__(16) unsigned short sBhi[256 * 32];  // 16 KB
    __shared__ __align__(16) unsigned short sBlo[256 * 32];  // 16 KB

    const int bc   = blockIdx.x;         // 0..767
    const int tid  = threadIdx.x;        // j (phase 1)
    const int lane = tid & 63;
    const int w    = tid >> 6;           // wave 0..3

    // ---------------- phase 1: T[p][tid] = sum_q K[bc,p,q]*Bt[tid,q] --------
    float breg[32];
    const float4* brow = (const float4*)(Bt + tid * 32);
    #pragma unroll
    for (int q4 = 0; q4 < 8; ++q4) {
        float4 v = brow[q4];
        breg[q4 * 4 + 0] = v.x;
        breg[q4 * 4 + 1] = v.y;
        breg[q4 * 4 + 2] = v.z;
        breg[q4 * 4 + 3] = v.w;
    }
    const float* Kbc = K + (size_t)bc * 1024;
    float treg[32];
    #pragma unroll
    for (int p = 0; p < 32; ++p) {
        float acc = 0.0f;
        #pragma unroll
        for (int q = 0; q < 32; ++q)
            acc += Kbc[p * 32 + q] * breg[q];
        treg[p] = acc;
    }
    // split to bf16 hi/lo, write B-fragment blocks: n=tid, c=k/8
    #pragma unroll
    for (int c = 0; c < 4; ++c) {
        bf16x8 vh, vl;
        #pragma unroll
        for (int jj = 0; jj < 8; ++jj) {
            float x = treg[c * 8 + jj];
            unsigned short h = f2bf_rne(x);
            vh[jj] = (short)h;
            vl[jj] = (short)f2bf_rne(x - bf2f(h));
        }
        int boff = (tid * 4 + (c ^ (tid & 3))) * 8;   // swizzled 16B block
        *(bf16x8*)&sBhi[boff] = vh;
        *(bf16x8*)&sBlo[boff] = vl;
    }
    __syncthreads();

    // ---------------- phase 2: MFMA ----------------------------------------
    const int m = lane & 15;     // A row-in-tile / D col-in-tile
    const int q = lane >> 4;     // k-chunk (A/B) / row-quad (D)

    // A-frags: Bu rows for tiles ti = 4w..4w+3, hi and lo. Same 64 KB for all
    // blocks -> L1/L2 resident after first touch.
    bf16x8 Ah[4], Al[4];
    #pragma unroll
    for (int a = 0; a < 4; ++a) {
        int row = (w * 4 + a) * 16 + m;
        Ah[a] = *(const bf16x8*)(Hi + row * 32 + q * 8);
        Al[a] = *(const bf16x8*)(Lo + row * 32 + q * 8);
    }

    float* outbc = out + (size_t)bc * 65536;
    for (int tj = 0; tj < 16; ++tj) {
        int n = tj * 16 + m;
        int boff = (n * 4 + (q ^ (n & 3))) * 8;
        bf16x8 Bh = *(const bf16x8*)&sBhi[boff];
        bf16x8 Bl = *(const bf16x8*)&sBlo[boff];
        #pragma unroll
        for (int a = 0; a < 4; ++a) {
            f32x4 acc = {0.0f, 0.0f, 0.0f, 0.0f};
            acc = __builtin_amdgcn_mfma_f32_16x16x32_bf16(Al[a], Bh, acc, 0, 0, 0);
            acc = __builtin_amdgcn_mfma_f32_16x16x32_bf16(Ah[a], Bl, acc, 0, 0, 0);
            acc = __builtin_amdgcn_mfma_f32_16x16x32_bf16(Ah[a], Bh, acc, 0, 0, 0);
            // D layout: col = lane&15 (= m), row = q*4 + r
            int row0 = (w * 4 + a) * 16 + q * 4;
            float* o = outbc + row0 * 256 + tj * 16 + m;
            o[0]   = acc[0];
            o[256] = acc[1];
            o[512] = acc[2];
            o[768] = acc[3];
        }
    }
}

extern "C" void kernel_launch(void* const* d_in, const int* in_sizes, int n_in,
                              void* d_out, int out_size, void* d_ws, size_t ws_size,
                              hipStream_t stream) {
    // d_in[0] = x (ignored), d_in[1] = K_mat (768*32*32 fp32)
    const float* K = (const float*)d_in[1];
    char* ws = (char*)d_ws;
    float*          Bt = (float*)ws;                      // 32 KB
    unsigned short* Hi = (unsigned short*)(ws + 32768);   // 16 KB
    unsigned short* Lo = (unsigned short*)(ws + 49152);   // 16 KB
    float* out = (float*)d_out;

    bez_basis_kernel<<<dim3(32), dim3(256), 0, stream>>>(Bt, Hi, Lo);
    bez_main_kernel<<<dim3(768), dim3(256), 0, stream>>>(K, Bt, Hi, Lo, out);
}

// Round 3
// 215.485 us; speedup vs baseline: 1.1724x; 1.0170x over previous
//
#include <hip/hip_runtime.h>

// BezierSurfaceFitter via MFMA, transposed-GEMM formulation.
// out[bc,i,j] = sum_p Bu[i,p]*T[bc,p,j];  T[bc,p,j] = sum_q K[bc,p,q]*Bv[j,q]
// Per bc we compute D = A*B with A = T^T (256j x 32p, from LDS, hi/lo bf16)
// and B = Bu^T (32p x 256i, from global hi/lo tables). D[j_local=q*4+r][i=m]
// => per lane 4 CONSECUTIVE j at fixed i => global_store_dwordx4 (1KB/instr).
// A-frags depend only on the wave's 4 j-tiles => 8 ds_read_b128/thread total.
// LDS chunk index XOR-swizzled with (j>>1)&3 => full 32-bank coverage
// (c^(tid&3) only reached 16 banks: bank=(16*tid+4*swz)%32 couples parity).

#define DEG 31

typedef short bf16x8 __attribute__((ext_vector_type(8)));  // 8 bf16 in 4 VGPRs
typedef float f32x4  __attribute__((ext_vector_type(4)));

__device__ __forceinline__ unsigned short f2bf_rne(float x) {
    unsigned int u = __float_as_uint(x);
    unsigned int r = (u + 0x7FFFu + ((u >> 16) & 1u)) >> 16;
    return (unsigned short)r;
}
__device__ __forceinline__ float bf2f(unsigned short h) {
    return __uint_as_float(((unsigned int)h) << 16);
}

// ---- kernel 1: Bernstein basis tables (fp32 + bf16 hi/lo) ------------------
__global__ __launch_bounds__(256) void bez_basis_kernel(
        float* __restrict__ Bt,            // (256,32) fp32
        unsigned short* __restrict__ Hi,   // (256,32) bf16 hi
        unsigned short* __restrict__ Lo) { // (256,32) bf16 lo
    int g = blockIdx.x * 256 + threadIdx.x;   // 0..8191
    int i = g >> 5;
    int k = g & 31;
    double t = ((double)i + 0.5) / 256.0;
    double coeff = 1.0;                    // C(31,k), exact in fp64
    for (int kk = 1; kk <= k; ++kk)
        coeff = coeff * (double)(DEG - kk + 1) / (double)kk;
    double tk = 1.0;
    for (int e = 0; e < k; ++e) tk *= t;
    double omt = 1.0 - t;
    double tq = 1.0;
    for (int e = 0; e < DEG - k; ++e) tq *= omt;
    float v = (float)(coeff * tk * tq);
    Bt[g] = v;
    unsigned short h = f2bf_rne(v);
    Hi[g] = h;
    Lo[g] = f2bf_rne(v - bf2f(h));
}

// ---- kernel 2: main --------------------------------------------------------
__global__ __launch_bounds__(256) void bez_main_kernel(
        const float* __restrict__ K,             // (768,32,32) fp32
        const float* __restrict__ Bt,            // (256,32) fp32
        const unsigned short* __restrict__ Hi,   // (256,32) bf16 hi
        const unsigned short* __restrict__ Lo,   // (256,32) bf16 lo
        float* __restrict__ out) {               // (768,256,256) fp32
    // T^T rows as A-operand fragments, hi/lo. Row j: 32 bf16 (64 B), chunk
    // c (8 bf16, 16 B) stored at swizzled slot c ^ ((j>>1)&3).
    __shared__ __align__(16) unsigned short sThi[256 * 32];  // 16 KB
    __shared__ __align__(16) unsigned short sTlo[256 * 32];  // 16 KB

    const int bc   = blockIdx.x;        // 0..767
    const int tid  = threadIdx.x;       // j in phase 1
    const int lane = tid & 63;
    const int w    = tid >> 6;          // wave 0..3

    // ------- phase 1: T[p][tid] = sum_q K[bc,p,q] * Bt[tid,q] (fp32 VALU) ---
    float breg[32];
    const float4* brow = (const float4*)(Bt + tid * 32);
    #pragma unroll
    for (int q4 = 0; q4 < 8; ++q4) {
        float4 v = brow[q4];
        breg[q4 * 4 + 0] = v.x;
        breg[q4 * 4 + 1] = v.y;
        breg[q4 * 4 + 2] = v.z;
        breg[q4 * 4 + 3] = v.w;
    }
    const float* Kbc = K + (size_t)bc * 1024;   // wave-uniform -> s_load
    float treg[32];
    #pragma unroll
    for (int p = 0; p < 32; ++p) {
        float acc = 0.0f;
        #pragma unroll
        for (int q = 0; q < 32; ++q)
            acc += Kbc[p * 32 + q] * breg[q];
        treg[p] = acc;
    }
    // split hi/lo, write A-fragment chunks (swizzled, conflict-free)
    const int jsw = (tid >> 1) & 3;
    #pragma unroll
    for (int c = 0; c < 4; ++c) {
        bf16x8 vh, vl;
        #pragma unroll
        for (int jj = 0; jj < 8; ++jj) {
            float x = treg[c * 8 + jj];
            unsigned short h = f2bf_rne(x);
            vh[jj] = (short)h;
            vl[jj] = (short)f2bf_rne(x - bf2f(h));
        }
        int off = tid * 32 + (c ^ jsw) * 8;
        *(bf16x8*)&sThi[off] = vh;
        *(bf16x8*)&sTlo[off] = vl;
    }
    __syncthreads();

    // ------- phase 2: D = T^T * Bu^T, tiles 16x16, K=32 (one MFMA k-step) ---
    const int m = lane & 15;     // i within column-tile / A row j within tile
    const int q = lane >> 4;     // k-chunk for A/B; row-quad for D

    // A-frags: T^T rows for this wave's 4 j-tiles (jt = 4w+a), from LDS.
    bf16x8 Th[4], Tl[4];
    #pragma unroll
    for (int a = 0; a < 4; ++a) {
        int j = (w * 4 + a) * 16 + m;
        int off = j * 32 + (q ^ ((j >> 1) & 3)) * 8;
        Th[a] = *(const bf16x8*)&sThi[off];
        Tl[a] = *(const bf16x8*)&sTlo[off];
    }

    float* outbc = out + (size_t)bc * 65536;
    for (int it = 0; it < 16; ++it) {
        int i = it * 16 + m;
        // B-frags: Bu row i, chunk q (global, 32KB table shared -> L1-hot)
        bf16x8 Bh = *(const bf16x8*)(Hi + i * 32 + q * 8);
        bf16x8 Bl = *(const bf16x8*)(Lo + i * 32 + q * 8);
        #pragma unroll
        for (int a = 0; a < 4; ++a) {
            f32x4 acc = {0.0f, 0.0f, 0.0f, 0.0f};
            acc = __builtin_amdgcn_mfma_f32_16x16x32_bf16(Tl[a], Bh, acc, 0, 0, 0);
            acc = __builtin_amdgcn_mfma_f32_16x16x32_bf16(Th[a], Bl, acc, 0, 0, 0);
            acc = __builtin_amdgcn_mfma_f32_16x16x32_bf16(Th[a], Bh, acc, 0, 0, 0);
            // D[row=q*4+r][col=m]: row -> j (consecutive in r), col -> i.
            float4 o4 = {acc[0], acc[1], acc[2], acc[3]};
            float* o = outbc + (size_t)i * 256 + (w * 4 + a) * 16 + q * 4;
            *(float4*)o = o4;   // 16B per lane; wave = 16 rows x 64B contiguous
        }
    }
}

extern "C" void kernel_launch(void* const* d_in, const int* in_sizes, int n_in,
                              void* d_out, int out_size, void* d_ws, size_t ws_size,
                              hipStream_t stream) {
    // d_in[0] = x (ignored), d_in[1] = K_mat (768*32*32 fp32)
    const float* K = (const float*)d_in[1];
    char* ws = (char*)d_ws;
    float*          Bt = (float*)ws;                      // 32 KB
    unsigned short* Hi = (unsigned short*)(ws + 32768);   // 16 KB
    unsigned short* Lo = (unsigned short*)(ws + 49152);   // 16 KB
    float* out = (float*)d_out;

    bez_basis_kernel<<<dim3(32), dim3(256), 0, stream>>>(Bt, Hi, Lo);
    bez_main_kernel<<<dim3(768), dim3(256), 0, stream>>>(K, Bt, Hi, Lo, out);
}